// Round 2
// baseline (688.753 us; speedup 1.0000x reference)
//
#include <hip/hip_runtime.h>

// Problem constants (match reference)
#define B_N 2048
#define C_N 64
#define D_N 1024
// K_ACTIVE=4, N_POS=12, N_NEG_PER=20
#define MARGIN_C 0.15f
#define INV_TEMP (1.0f / 0.07f)

typedef float v4f __attribute__((ext_vector_type(4)));

__device__ __forceinline__ float wred(float v) {
#pragma unroll
    for (int off = 32; off > 0; off >>= 1) v += __shfl_xor(v, off, 64);
    return v;
}

__device__ __forceinline__ v4f nt_load4(const v4f* p) {
    return __builtin_nontemporal_load(p);
}

// R6 (resubmit after infra failure):
// (a) stream loads for the wave's first two rows issued FIRST (preamble
//     latency hides under them); (b) emb-independent loss terms (BCE/margin/
//     topk, spatial, network) moved BEFORE the stream so they fill load-wait
//     slots instead of serializing in the tail; (c) pair-fold cross-lane
//     reduction: 9 shuffles instead of 30 per row, bit-identical tree sums;
//     (d) active rows sourced from registers (frag) instead of re-fetching
//     ~32 MiB through the NT stream.
__global__ __launch_bounds__(256, 4)
void loss_kernel(const float* __restrict__ pred,
                 const int*   __restrict__ lab,
                 const float* __restrict__ emb,
                 const float* __restrict__ cpos,
                 const float* __restrict__ conn,
                 float* __restrict__ partial)
{
    __shared__ v4f   s_frag4[1024];   // 16 KB: the 4 active rows, staged once
    __shared__ float s_p[64];
    __shared__ int   s_inact[60];
    __shared__ float s_dn[64][5];     // [c][j<4]=dot(emb_c, emb_act_j), [c][4]=|emb_c|^2
    __shared__ float s_pos[192];      // 64 x 3 channel positions
    __shared__ float s_part[6];

    const int tid  = threadIdx.x;
    const int w    = tid >> 6;
    const int lane = tid & 63;
    const int b    = blockIdx.x;
    const int w16  = w * 16;

    const v4f* base = (const v4f*)emb + (long)b * 64 * 256;

    // ---- R6a: issue the wave's first two stream rows before ANY other work.
    v4f bufA[4], bufB[4];
#pragma unroll
    for (int t = 0; t < 4; t++) bufA[t] = nt_load4(base + (w16 + 0) * 256 + lane + 64 * t);
#pragma unroll
    for (int t = 0; t < 4; t++) bufB[t] = nt_load4(base + (w16 + 1) * 256 + lane + 64 * t);

    // ---- preamble ----
    const float p_lane = pred[b * 64 + lane];
    const int   l_lane = lab[b * 64 + lane];
    if (tid >= 64 && tid < 256) s_pos[tid - 64] = cpos[tid - 64];

    const unsigned long long mask = __ballot(l_lane != 0);   // same in all waves
    unsigned long long mtmp = mask;
    int act[4];
#pragma unroll
    for (int j = 0; j < 4; j++) { act[j] = __builtin_ctzll(mtmp); mtmp &= mtmp - 1; }

    // cooperative staging of the 4 active rows into LDS
#pragma unroll
    for (int k = 0; k < 4; k++) s_frag4[k * 256 + tid] = base[act[k] * 256 + tid];

    if (w == 0) {
        s_p[lane] = p_lane;
        if (!((mask >> lane) & 1ull)) {
            int r = __popcll(~mask & ((1ull << lane) - 1ull));  // rank among inactive
            s_inact[r] = lane;
        }
    }
    __syncthreads();

    // ---- R6b: emb-independent loss terms while first stream rows in flight ----
    if (w == 1) {
        // score (BCE), margin, top-k
        float sc = l_lane ? -logf(p_lane) : -log1pf(-p_lane);
        sc = wred(sc);
        float s1 = wred(l_lane ? p_lane : 0.0f); // sum over active
        float s2 = wred(p_lane);                 // total sum
        // top-4 via 4 argmax rounds (tie -> lower index, matches lax.top_k)
        float pv = p_lane;
        int inter = 0;
#pragma unroll
        for (int it = 0; it < 4; it++) {
            float v = pv;
            int   ix = lane;
#pragma unroll
            for (int off = 32; off > 0; off >>= 1) {
                float ov = __shfl_xor(v, off, 64);
                int   oi = __shfl_xor(ix, off, 64);
                if (ov > v || (ov == v && oi < ix)) { v = ov; ix = oi; }
            }
            if (lane == ix) pv = -1e30f;
            if ((mask >> ix) & 1ull) inter++;
        }
        if (lane == 0) {
            s_part[1] = sc;
            float am = s1 * (1.0f / 4.0f);
            float im = (s2 - s1) * (1.0f / 60.0f);
            s_part[2] = fmaxf(MARGIN_C - (am - im), 0.0f);
            float fi = (float)inter;
            float un = (float)(8 - inter);
            s_part[3] = 1.0f - fi / (un + 1e-8f);
        }
    } else if (w == 2) {
        // spatial: pair_sum = sum_{i,j} m_i m_j dist(i,j), dist on the fly
        bool  mj = p_lane > 0.5f;
        float px = s_pos[lane * 3 + 0];
        float py = s_pos[lane * 3 + 1];
        float pz = s_pos[lane * 3 + 2];
        float tj = 0.0f;
        for (int i = 0; i < 64; i++) {
            float dx = s_pos[i * 3 + 0] - px;
            float dy = s_pos[i * 3 + 1] - py;
            float dz = s_pos[i * 3 + 2] - pz;
            float d2 = dx * dx + dy * dy + dz * dz;
            bool on = (i != lane) && (s_p[i] > 0.5f);
            tj += on ? sqrtf(d2) : 0.0f;
        }
        float pair = wred(mj ? tj : 0.0f);
        unsigned long long bal = __ballot(mj);
        int nm = __popcll(bal);
        if (lane == 0) {
            s_part[4] = (nm >= 2) ? pair / fmaxf((float)nm * (float)(nm - 1), 1.0f) : 0.0f;
        }
    } else if (w == 3) {
        // network coherence: p^T W p
        float tj = 0.0f;
        for (int i = 0; i < 64; i++) tj += s_p[i] * conn[i * 64 + lane];
        float coh = wred(tj * p_lane);
        if (lane == 0) s_part[5] = -coh * (1.0f / 4096.0f);
    }

    // ---- fragments LDS -> registers ----
    v4f frag[4][4];
#pragma unroll
    for (int j = 0; j < 4; j++)
#pragma unroll
        for (int t = 0; t < 4; t++) frag[j][t] = s_frag4[j * 256 + lane + 64 * t];

    // ---- main stream: wave w owns contiguous rows [16w,16w+16) ----
    auto compute_row = [&](const v4f* buf, int c) {
        float a0 = 0.f, a1 = 0.f, a2 = 0.f, a3 = 0.f, ns = 0.f;
#pragma unroll
        for (int t = 0; t < 4; t++) {
            v4f u = buf[t];
            ns += u.x * u.x + u.y * u.y + u.z * u.z + u.w * u.w;
            a0 += u.x * frag[0][t].x + u.y * frag[0][t].y + u.z * frag[0][t].z + u.w * frag[0][t].w;
            a1 += u.x * frag[1][t].x + u.y * frag[1][t].y + u.z * frag[1][t].z + u.w * frag[1][t].w;
            a2 += u.x * frag[2][t].x + u.y * frag[2][t].y + u.z * frag[2][t].z + u.w * frag[2][t].w;
            a3 += u.x * frag[3][t].x + u.y * frag[3][t].y + u.z * frag[3][t].z + u.w * frag[3][t].w;
        }
        // R6c: pair-fold reduction. Same pairing tree (bit 5 -> 4 -> 3 -> 2 ->
        // 1 -> 0) as the old 6-level butterfly -> bit-identical sums, but
        // 9 shuffles instead of 30.
        const bool hi32 = (lane & 32) != 0;
        float u01 = hi32 ? a1 : a0;          // value this half keeps
        float v01 = hi32 ? a0 : a1;          // value the other half needs
        u01 += __shfl_xor(v01, 32, 64);      // lanes<32: a0 pairs; lanes>=32: a1 pairs
        float u23 = hi32 ? a3 : a2;
        float v23 = hi32 ? a2 : a3;
        u23 += __shfl_xor(v23, 32, 64);
        ns  += __shfl_xor(ns, 32, 64);

        const bool hi16 = (lane & 16) != 0;
        float x = hi16 ? u23 : u01;
        float y = hi16 ? u01 : u23;
        x  += __shfl_xor(y, 16, 64);         // quarters: a0 | a2 | a1 | a3
        ns += __shfl_xor(ns, 16, 64);

        const bool hi8 = (lane & 8) != 0;
        float z  = hi8 ? ns : x;
        float zz = hi8 ? x : ns;
        z += __shfl_xor(zz, 8, 64);          // eighths: a0,ns,a2,ns,a1,ns,a3,ns

        z += __shfl_xor(z, 4, 64);
        z += __shfl_xor(z, 2, 64);
        z += __shfl_xor(z, 1, 64);
        // lane 0 -> a0, 8 -> ns, 16 -> a2, 32 -> a1, 48 -> a3
        if ((lane & 7) == 0) {
            int g = lane >> 3;                       // 0,1,2,3,4,5,6,7
            int slot = (g == 1) ? 4 : ((g & 2) | (g >> 2)); // 0->0,2->2,4->1,6->3
            if (!(g & 1) || g == 1) s_dn[c][slot] = z;
        }
    };

    // R6d: active rows come from frag (same bits, same lane+64t layout) --
    // skips their redundant HBM fetch. act[] is wave-uniform -> scalar branch.
    auto fill_row = [&](v4f* buf, int c) {
        if (c == act[0]) {
#pragma unroll
            for (int t = 0; t < 4; t++) buf[t] = frag[0][t];
        } else if (c == act[1]) {
#pragma unroll
            for (int t = 0; t < 4; t++) buf[t] = frag[1][t];
        } else if (c == act[2]) {
#pragma unroll
            for (int t = 0; t < 4; t++) buf[t] = frag[2][t];
        } else if (c == act[3]) {
#pragma unroll
            for (int t = 0; t < 4; t++) buf[t] = frag[3][t];
        } else {
#pragma unroll
            for (int t = 0; t < 4; t++) buf[t] = nt_load4(base + c * 256 + lane + 64 * t);
        }
    };

#pragma unroll 1
    for (int i = 0; i < 16; i += 2) {
        const int c0 = w16 + i;
        compute_row(bufA, c0);
        if (i < 14) fill_row(bufA, c0 + 2);   // in flight while computing bufB
        compute_row(bufB, c0 + 1);
        if (i < 14) fill_row(bufB, c0 + 3);
    }
    __syncthreads();

    // ---- tail: only the contrastive term still depends on the stream ----
    if (w == 0) {
        float ce = 0.0f;
        if (lane < 12) {
            int k = lane / 3;
            int r = lane % 3;
            int m = r + ((r >= k) ? 1 : 0); // r-th column != k
            float nk = fmaxf(sqrtf(s_dn[act[k]][4]), 1e-12f);
            float nm = fmaxf(sqrtf(s_dn[act[m]][4]), 1e-12f);
            float posv = s_dn[act[k]][m] / (nk * nm) * INV_TEMP;
            float neg[20];
            float mx = posv;
            int base2 = r * 20;
#pragma unroll
            for (int t = 0; t < 20; t++) {
                int c = s_inact[base2 + t];
                float nc = fmaxf(sqrtf(s_dn[c][4]), 1e-12f);
                neg[t] = s_dn[c][k] / (nk * nc) * INV_TEMP;
                mx = fmaxf(mx, neg[t]);
            }
            float sum = __expf(posv - mx);
#pragma unroll
            for (int t = 0; t < 20; t++) sum += __expf(neg[t] - mx);
            ce = logf(sum) + mx - posv;
        }
        ce = wred(ce);
        if (lane == 0) s_part[0] = ce;
    }
    __syncthreads();

    if (tid == 0) {
        // per-row loss contribution (unscaled by 1/B; finalize kernel does that)
        partial[b] = 3.0f * s_part[1] * (1.0f / 64.0f)  // score (per-row mean over C)
                   + s_part[2]                           // margin
                   + 2.0f * s_part[3]                    // topk
                   + s_part[0] * (1.0f / 12.0f)          // contrastive
                   + 0.5f * s_part[4]                    // spatial
                   + 0.5f * s_part[5];                   // network
    }
}

__global__ void finalize_kernel(const float* __restrict__ partial, float* __restrict__ out) {
    __shared__ float sm[4];
    const int tid  = threadIdx.x;
    const int w    = tid >> 6;
    const int lane = tid & 63;
    float s = 0.0f;
    for (int i = tid; i < B_N; i += 256) s += partial[i];
    s = wred(s);
    if (lane == 0) sm[w] = s;
    __syncthreads();
    if (tid == 0) out[0] = (sm[0] + sm[1] + sm[2] + sm[3]) * (1.0f / (float)B_N);
}

extern "C" void kernel_launch(void* const* d_in, const int* in_sizes, int n_in,
                              void* d_out, int out_size, void* d_ws, size_t ws_size,
                              hipStream_t stream) {
    const float* pred = (const float*)d_in[0];
    const int*   lab  = (const int*)d_in[1];
    const float* emb  = (const float*)d_in[2];
    const float* cpos = (const float*)d_in[3];
    const float* conn = (const float*)d_in[4];
    float* out = (float*)d_out;
    float* partial = (float*)d_ws;  // 2048 floats = 8 KB, well within ws_size

    loss_kernel<<<B_N, 256, 0, stream>>>(pred, lab, emb, cpos, conn, partial);
    finalize_kernel<<<1, 256, 0, stream>>>(partial, out);
}

// Round 3
// 686.710 us; speedup vs baseline: 1.0030x; 1.0030x over previous
//
#include <hip/hip_runtime.h>

// Problem constants (match reference)
#define B_N 2048
#define C_N 64
#define D_N 1024
// K_ACTIVE=4, N_POS=12, N_NEG_PER=20
#define MARGIN_C 0.15f
#define INV_TEMP (1.0f / 0.07f)

typedef float v4f __attribute__((ext_vector_type(4)));

__device__ __forceinline__ float wred(float v) {
#pragma unroll
    for (int off = 32; off > 0; off >>= 1) v += __shfl_xor(v, off, 64);
    return v;
}

__device__ __forceinline__ v4f nt_load4(const v4f* p) {
    return __builtin_nontemporal_load(p);
}

// R7 = R5 schedule (preamble -> stage -> frag -> stream -> tail; that ordering
// benched 678 us; R6's early-load reordering cost +10 us, reverted) keeping
// only the two hot-loop-local wins validated by R6's absmax=0.0:
//   R6c: pair-fold cross-lane reduction, 9 shuffles/row instead of 30,
//        bit-identical pairing tree (bit 5 -> 4 -> 3 -> 2 -> 1 -> 0).
//   R6d: active rows sourced from frag registers (wave-uniform scalar branch)
//        instead of re-fetching ~32 MiB through the NT stream.
__global__ __launch_bounds__(256, 4)
void loss_kernel(const float* __restrict__ pred,
                 const int*   __restrict__ lab,
                 const float* __restrict__ emb,
                 const float* __restrict__ cpos,
                 const float* __restrict__ conn,
                 float* __restrict__ partial)
{
    __shared__ v4f   s_frag4[1024];   // 16 KB: the 4 active rows, staged once
    __shared__ float s_p[64];
    __shared__ int   s_inact[60];
    __shared__ float s_dn[64][5];     // [c][j<4]=dot(emb_c, emb_act_j), [c][4]=|emb_c|^2
    __shared__ float s_pos[192];      // 64 x 3 channel positions
    __shared__ float s_part[6];

    const int tid  = threadIdx.x;
    const int w    = tid >> 6;
    const int lane = tid & 63;
    const int b    = blockIdx.x;
    const int w16  = w * 16;

    // ---- preamble: fully parallel (R5 ordering) ----
    const float p_lane = pred[b * 64 + lane];
    const int   l_lane = lab[b * 64 + lane];
    if (tid >= 64 && tid < 256) s_pos[tid - 64] = cpos[tid - 64];

    const unsigned long long mask = __ballot(l_lane != 0);   // same in all waves
    unsigned long long mtmp = mask;
    int act[4];
#pragma unroll
    for (int j = 0; j < 4; j++) { act[j] = __builtin_ctzll(mtmp); mtmp &= mtmp - 1; }

    // cooperative staging of the 4 active rows into LDS
    const v4f* base = (const v4f*)emb + (long)b * 64 * 256;
#pragma unroll
    for (int k = 0; k < 4; k++) s_frag4[k * 256 + tid] = base[act[k] * 256 + tid];

    if (w == 0) {
        s_p[lane] = p_lane;
        if (!((mask >> lane) & 1ull)) {
            int r = __popcll(~mask & ((1ull << lane) - 1ull));  // rank among inactive
            s_inact[r] = lane;
        }
    }
    __syncthreads();

    // ---- fragments LDS -> registers ----
    v4f frag[4][4];
#pragma unroll
    for (int j = 0; j < 4; j++)
#pragma unroll
        for (int t = 0; t < 4; t++) frag[j][t] = s_frag4[j * 256 + lane + 64 * t];

    // ---- main stream: wave w owns contiguous rows [16w, 16w+16) ----
    auto compute_row = [&](const v4f* buf, int c) {
        float a0 = 0.f, a1 = 0.f, a2 = 0.f, a3 = 0.f, ns = 0.f;
#pragma unroll
        for (int t = 0; t < 4; t++) {
            v4f u = buf[t];
            ns += u.x * u.x + u.y * u.y + u.z * u.z + u.w * u.w;
            a0 += u.x * frag[0][t].x + u.y * frag[0][t].y + u.z * frag[0][t].z + u.w * frag[0][t].w;
            a1 += u.x * frag[1][t].x + u.y * frag[1][t].y + u.z * frag[1][t].z + u.w * frag[1][t].w;
            a2 += u.x * frag[2][t].x + u.y * frag[2][t].y + u.z * frag[2][t].z + u.w * frag[2][t].w;
            a3 += u.x * frag[3][t].x + u.y * frag[3][t].y + u.z * frag[3][t].z + u.w * frag[3][t].w;
        }
        // R6c pair-fold reduction (bit-identical to the old 6-level butterfly).
        const bool hi32 = (lane & 32) != 0;
        float u01 = hi32 ? a1 : a0;          // value this half keeps
        float v01 = hi32 ? a0 : a1;          // value the other half needs
        u01 += __shfl_xor(v01, 32, 64);      // lanes<32: a0 pairs; lanes>=32: a1 pairs
        float u23 = hi32 ? a3 : a2;
        float v23 = hi32 ? a2 : a3;
        u23 += __shfl_xor(v23, 32, 64);
        ns  += __shfl_xor(ns, 32, 64);

        const bool hi16 = (lane & 16) != 0;
        float x = hi16 ? u23 : u01;
        float y = hi16 ? u01 : u23;
        x  += __shfl_xor(y, 16, 64);         // quarters: a0 | a2 | a1 | a3
        ns += __shfl_xor(ns, 16, 64);

        const bool hi8 = (lane & 8) != 0;
        float z  = hi8 ? ns : x;
        float zz = hi8 ? x : ns;
        z += __shfl_xor(zz, 8, 64);          // eighths: a0,ns,a2,ns,a1,ns,a3,ns

        z += __shfl_xor(z, 4, 64);
        z += __shfl_xor(z, 2, 64);
        z += __shfl_xor(z, 1, 64);
        // lane 0 -> a0, 8 -> ns, 16 -> a2, 32 -> a1, 48 -> a3
        if ((lane & 7) == 0) {
            int g = lane >> 3;                       // 0..7
            int slot = (g == 1) ? 4 : ((g & 2) | (g >> 2)); // 0->0,2->2,4->1,6->3
            if (!(g & 1) || g == 1) s_dn[c][slot] = z;
        }
    };

    // R6d: active rows come from frag (same bits, same lane+64t layout) --
    // skips their redundant HBM fetch. act[] is wave-uniform -> scalar branch.
    auto fill_row = [&](v4f* buf, int c) {
        if (c == act[0]) {
#pragma unroll
            for (int t = 0; t < 4; t++) buf[t] = frag[0][t];
        } else if (c == act[1]) {
#pragma unroll
            for (int t = 0; t < 4; t++) buf[t] = frag[1][t];
        } else if (c == act[2]) {
#pragma unroll
            for (int t = 0; t < 4; t++) buf[t] = frag[2][t];
        } else if (c == act[3]) {
#pragma unroll
            for (int t = 0; t < 4; t++) buf[t] = frag[3][t];
        } else {
#pragma unroll
            for (int t = 0; t < 4; t++) buf[t] = nt_load4(base + c * 256 + lane + 64 * t);
        }
    };

    v4f bufA[4], bufB[4];
    fill_row(bufA, w16);

#pragma unroll 1
    for (int i = 0; i < 16; i += 2) {
        const int c0 = w16 + i;
        fill_row(bufB, c0 + 1);               // in flight while computing bufA
        compute_row(bufA, c0);
        if (i < 14) fill_row(bufA, c0 + 2);   // in flight while computing bufB
        compute_row(bufB, c0 + 1);
    }
    __syncthreads();

    // ---- per-wave loss terms (R5 ordering: after the stream) ----
    if (w == 0) {
        // contrastive: 12 (anchor, positive) pairs, 20 negatives each
        float ce = 0.0f;
        if (lane < 12) {
            int k = lane / 3;
            int r = lane % 3;
            int m = r + ((r >= k) ? 1 : 0); // r-th column != k
            float nk = fmaxf(sqrtf(s_dn[act[k]][4]), 1e-12f);
            float nm = fmaxf(sqrtf(s_dn[act[m]][4]), 1e-12f);
            float posv = s_dn[act[k]][m] / (nk * nm) * INV_TEMP;
            float neg[20];
            float mx = posv;
            int base2 = r * 20;
#pragma unroll
            for (int t = 0; t < 20; t++) {
                int c = s_inact[base2 + t];
                float nc = fmaxf(sqrtf(s_dn[c][4]), 1e-12f);
                neg[t] = s_dn[c][k] / (nk * nc) * INV_TEMP;
                mx = fmaxf(mx, neg[t]);
            }
            float sum = __expf(posv - mx);
#pragma unroll
            for (int t = 0; t < 20; t++) sum += __expf(neg[t] - mx);
            ce = logf(sum) + mx - posv;
        }
        ce = wred(ce);
        if (lane == 0) s_part[0] = ce;
    } else if (w == 1) {
        // score (BCE), margin, top-k
        float sc = l_lane ? -logf(p_lane) : -log1pf(-p_lane);
        sc = wred(sc);
        float s1 = wred(l_lane ? p_lane : 0.0f); // sum over active
        float s2 = wred(p_lane);                 // total sum
        // top-4 via 4 argmax rounds (tie -> lower index, matches lax.top_k)
        float pv = p_lane;
        int inter = 0;
#pragma unroll
        for (int it = 0; it < 4; it++) {
            float v = pv;
            int   ix = lane;
#pragma unroll
            for (int off = 32; off > 0; off >>= 1) {
                float ov = __shfl_xor(v, off, 64);
                int   oi = __shfl_xor(ix, off, 64);
                if (ov > v || (ov == v && oi < ix)) { v = ov; ix = oi; }
            }
            if (lane == ix) pv = -1e30f;
            if ((mask >> ix) & 1ull) inter++;
        }
        if (lane == 0) {
            s_part[1] = sc;
            float am = s1 * (1.0f / 4.0f);
            float im = (s2 - s1) * (1.0f / 60.0f);
            s_part[2] = fmaxf(MARGIN_C - (am - im), 0.0f);
            float fi = (float)inter;
            float un = (float)(8 - inter);
            s_part[3] = 1.0f - fi / (un + 1e-8f);
        }
    } else if (w == 2) {
        // spatial: pair_sum = sum_{i,j} m_i m_j dist(i,j), dist on the fly
        bool  mj = p_lane > 0.5f;
        float px = s_pos[lane * 3 + 0];
        float py = s_pos[lane * 3 + 1];
        float pz = s_pos[lane * 3 + 2];
        float tj = 0.0f;
        for (int i = 0; i < 64; i++) {
            float dx = s_pos[i * 3 + 0] - px;
            float dy = s_pos[i * 3 + 1] - py;
            float dz = s_pos[i * 3 + 2] - pz;
            float d2 = dx * dx + dy * dy + dz * dz;
            bool on = (i != lane) && (s_p[i] > 0.5f);
            tj += on ? sqrtf(d2) : 0.0f;
        }
        float pair = wred(mj ? tj : 0.0f);
        unsigned long long bal = __ballot(mj);
        int nm = __popcll(bal);
        if (lane == 0) {
            s_part[4] = (nm >= 2) ? pair / fmaxf((float)nm * (float)(nm - 1), 1.0f) : 0.0f;
        }
    } else {
        // network coherence: p^T W p
        float tj = 0.0f;
        for (int i = 0; i < 64; i++) tj += s_p[i] * conn[i * 64 + lane];
        float coh = wred(tj * p_lane);
        if (lane == 0) s_part[5] = -coh * (1.0f / 4096.0f);
    }
    __syncthreads();

    if (tid == 0) {
        // per-row loss contribution (unscaled by 1/B; finalize kernel does that)
        partial[b] = 3.0f * s_part[1] * (1.0f / 64.0f)  // score (per-row mean over C)
                   + s_part[2]                           // margin
                   + 2.0f * s_part[3]                    // topk
                   + s_part[0] * (1.0f / 12.0f)          // contrastive
                   + 0.5f * s_part[4]                    // spatial
                   + 0.5f * s_part[5];                   // network
    }
}

__global__ void finalize_kernel(const float* __restrict__ partial, float* __restrict__ out) {
    __shared__ float sm[4];
    const int tid  = threadIdx.x;
    const int w    = tid >> 6;
    const int lane = tid & 63;
    float s = 0.0f;
    for (int i = tid; i < B_N; i += 256) s += partial[i];
    s = wred(s);
    if (lane == 0) sm[w] = s;
    __syncthreads();
    if (tid == 0) out[0] = (sm[0] + sm[1] + sm[2] + sm[3]) * (1.0f / (float)B_N);
}

extern "C" void kernel_launch(void* const* d_in, const int* in_sizes, int n_in,
                              void* d_out, int out_size, void* d_ws, size_t ws_size,
                              hipStream_t stream) {
    const float* pred = (const float*)d_in[0];
    const int*   lab  = (const int*)d_in[1];
    const float* emb  = (const float*)d_in[2];
    const float* cpos = (const float*)d_in[3];
    const float* conn = (const float*)d_in[4];
    float* out = (float*)d_out;
    float* partial = (float*)d_ws;  // 2048 floats = 8 KB, well within ws_size

    loss_kernel<<<B_N, 256, 0, stream>>>(pred, lab, emb, cpos, conn, partial);
    finalize_kernel<<<1, 256, 0, stream>>>(partial, out);
}

// Round 4
// 676.365 us; speedup vs baseline: 1.0183x; 1.0153x over previous
//
#include <hip/hip_runtime.h>

// Problem constants (match reference)
#define B_N 2048
#define C_N 64
#define D_N 1024
// K_ACTIVE=4, N_POS=12, N_NEG_PER=20
#define MARGIN_C 0.15f
#define INV_TEMP (1.0f / 0.07f)

typedef float v4f __attribute__((ext_vector_type(4)));

__device__ __forceinline__ float wred(float v) {
#pragma unroll
    for (int off = 32; off > 0; off >>= 1) v += __shfl_xor(v, off, 64);
    return v;
}

__device__ __forceinline__ v4f nt_load4(const v4f* p) {
    return __builtin_nontemporal_load(p);
}

// R8 = exact R5 stream structure (straight-line unconditional NT loads --
// the 678 us configuration; R6d's branchy fill_row broke the load pipeline
// via exec-mask branches around every load and cost ~+8 us, now removed)
// + R6c only: pair-fold cross-lane reduction, 9 shuffles/row instead of 30,
// bit-identical pairing tree (validated absmax=0.0 on HW in R6 and R7).
__global__ __launch_bounds__(256, 4)
void loss_kernel(const float* __restrict__ pred,
                 const int*   __restrict__ lab,
                 const float* __restrict__ emb,
                 const float* __restrict__ cpos,
                 const float* __restrict__ conn,
                 float* __restrict__ partial)
{
    __shared__ v4f   s_frag4[1024];   // 16 KB: the 4 active rows, staged once
    __shared__ float s_p[64];
    __shared__ int   s_inact[60];
    __shared__ float s_dn[64][5];     // [c][j<4]=dot(emb_c, emb_act_j), [c][4]=|emb_c|^2
    __shared__ float s_pos[192];      // 64 x 3 channel positions
    __shared__ float s_part[6];

    const int tid  = threadIdx.x;
    const int w    = tid >> 6;
    const int lane = tid & 63;
    const int b    = blockIdx.x;

    // ---- preamble: fully parallel (R5 ordering) ----
    const float p_lane = pred[b * 64 + lane];
    const int   l_lane = lab[b * 64 + lane];
    if (tid >= 64 && tid < 256) s_pos[tid - 64] = cpos[tid - 64];

    const unsigned long long mask = __ballot(l_lane != 0);   // same in all waves
    unsigned long long mtmp = mask;
    int act[4];
#pragma unroll
    for (int j = 0; j < 4; j++) { act[j] = __builtin_ctzll(mtmp); mtmp &= mtmp - 1; }

    // cooperative staging of the 4 active rows into LDS
    const v4f* base = (const v4f*)emb + (long)b * 64 * 256;
#pragma unroll
    for (int k = 0; k < 4; k++) s_frag4[k * 256 + tid] = base[act[k] * 256 + tid];

    if (w == 0) {
        s_p[lane] = p_lane;
        if (!((mask >> lane) & 1ull)) {
            int r = __popcll(~mask & ((1ull << lane) - 1ull));  // rank among inactive
            s_inact[r] = lane;
        }
    }
    __syncthreads();

    // ---- fragments LDS -> registers ----
    v4f frag[4][4];
#pragma unroll
    for (int j = 0; j < 4; j++)
#pragma unroll
        for (int t = 0; t < 4; t++) frag[j][t] = s_frag4[j * 256 + lane + 64 * t];

    // ---- main stream: wave w owns contiguous rows [16w, 16w+16), 1-ahead prefetch ----
    auto compute_row = [&](const v4f* buf, int c) {
        float a0 = 0.f, a1 = 0.f, a2 = 0.f, a3 = 0.f, ns = 0.f;
#pragma unroll
        for (int t = 0; t < 4; t++) {
            v4f u = buf[t];
            ns += u.x * u.x + u.y * u.y + u.z * u.z + u.w * u.w;
            a0 += u.x * frag[0][t].x + u.y * frag[0][t].y + u.z * frag[0][t].z + u.w * frag[0][t].w;
            a1 += u.x * frag[1][t].x + u.y * frag[1][t].y + u.z * frag[1][t].z + u.w * frag[1][t].w;
            a2 += u.x * frag[2][t].x + u.y * frag[2][t].y + u.z * frag[2][t].z + u.w * frag[2][t].w;
            a3 += u.x * frag[3][t].x + u.y * frag[3][t].y + u.z * frag[3][t].z + u.w * frag[3][t].w;
        }
        // R6c pair-fold reduction. Same pairing tree (bit 5 -> 4 -> 3 -> 2 ->
        // 1 -> 0) as the old 6-level butterfly -> bit-identical sums, but
        // 9 shuffles instead of 30. HW-validated (absmax=0.0, R6 & R7).
        const bool hi32 = (lane & 32) != 0;
        float u01 = hi32 ? a1 : a0;          // value this half keeps
        float v01 = hi32 ? a0 : a1;          // value the other half needs
        u01 += __shfl_xor(v01, 32, 64);      // lanes<32: a0 pairs; lanes>=32: a1 pairs
        float u23 = hi32 ? a3 : a2;
        float v23 = hi32 ? a2 : a3;
        u23 += __shfl_xor(v23, 32, 64);
        ns  += __shfl_xor(ns, 32, 64);

        const bool hi16 = (lane & 16) != 0;
        float x = hi16 ? u23 : u01;
        float y = hi16 ? u01 : u23;
        x  += __shfl_xor(y, 16, 64);         // quarters: a0 | a2 | a1 | a3
        ns += __shfl_xor(ns, 16, 64);

        const bool hi8 = (lane & 8) != 0;
        float z  = hi8 ? ns : x;
        float zz = hi8 ? x : ns;
        z += __shfl_xor(zz, 8, 64);          // eighths: a0,ns,a2,ns,a1,ns,a3,ns

        z += __shfl_xor(z, 4, 64);
        z += __shfl_xor(z, 2, 64);
        z += __shfl_xor(z, 1, 64);
        // lane 0 -> a0, 8 -> ns, 16 -> a2, 32 -> a1, 48 -> a3
        if ((lane & 7) == 0) {
            int g = lane >> 3;                       // 0..7
            int slot = (g == 1) ? 4 : ((g & 2) | (g >> 2)); // 0->0,2->2,4->1,6->3
            if (!(g & 1) || g == 1) s_dn[c][slot] = z;
        }
    };

    const v4f* wbase = base + (w * 16) * 256;   // wave's contiguous 64 KB region
    v4f bufA[4], bufB[4];
#pragma unroll
    for (int t = 0; t < 4; t++) bufA[t] = nt_load4(wbase + lane + 64 * t);

#pragma unroll 1
    for (int i = 0; i < 16; i += 2) {
        const int c0 = w * 16 + i;
        {   // prefetch row i+1 while computing row i
            const v4f* s = wbase + (i + 1) * 256;
#pragma unroll
            for (int t = 0; t < 4; t++) bufB[t] = nt_load4(s + lane + 64 * t);
        }
        compute_row(bufA, c0);
        if (i < 14) {   // prefetch row i+2 while computing row i+1
            const v4f* s = wbase + (i + 2) * 256;
#pragma unroll
            for (int t = 0; t < 4; t++) bufA[t] = nt_load4(s + lane + 64 * t);
        }
        compute_row(bufB, c0 + 1);
    }
    __syncthreads();

    // ---- per-wave loss terms ----
    if (w == 0) {
        // contrastive: 12 (anchor, positive) pairs, 20 negatives each
        float ce = 0.0f;
        if (lane < 12) {
            int k = lane / 3;
            int r = lane % 3;
            int m = r + ((r >= k) ? 1 : 0); // r-th column != k
            float nk = fmaxf(sqrtf(s_dn[act[k]][4]), 1e-12f);
            float nm = fmaxf(sqrtf(s_dn[act[m]][4]), 1e-12f);
            float posv = s_dn[act[k]][m] / (nk * nm) * INV_TEMP;
            float neg[20];
            float mx = posv;
            int base2 = r * 20;
#pragma unroll
            for (int t = 0; t < 20; t++) {
                int c = s_inact[base2 + t];
                float nc = fmaxf(sqrtf(s_dn[c][4]), 1e-12f);
                neg[t] = s_dn[c][k] / (nk * nc) * INV_TEMP;
                mx = fmaxf(mx, neg[t]);
            }
            float sum = __expf(posv - mx);
#pragma unroll
            for (int t = 0; t < 20; t++) sum += __expf(neg[t] - mx);
            ce = logf(sum) + mx - posv;
        }
        ce = wred(ce);
        if (lane == 0) s_part[0] = ce;
    } else if (w == 1) {
        // score (BCE), margin, top-k
        float sc = l_lane ? -logf(p_lane) : -log1pf(-p_lane);
        sc = wred(sc);
        float s1 = wred(l_lane ? p_lane : 0.0f); // sum over active
        float s2 = wred(p_lane);                 // total sum
        // top-4 via 4 argmax rounds (tie -> lower index, matches lax.top_k)
        float pv = p_lane;
        int inter = 0;
#pragma unroll
        for (int it = 0; it < 4; it++) {
            float v = pv;
            int   ix = lane;
#pragma unroll
            for (int off = 32; off > 0; off >>= 1) {
                float ov = __shfl_xor(v, off, 64);
                int   oi = __shfl_xor(ix, off, 64);
                if (ov > v || (ov == v && oi < ix)) { v = ov; ix = oi; }
            }
            if (lane == ix) pv = -1e30f;
            if ((mask >> ix) & 1ull) inter++;
        }
        if (lane == 0) {
            s_part[1] = sc;
            float am = s1 * (1.0f / 4.0f);
            float im = (s2 - s1) * (1.0f / 60.0f);
            s_part[2] = fmaxf(MARGIN_C - (am - im), 0.0f);
            float fi = (float)inter;
            float un = (float)(8 - inter);
            s_part[3] = 1.0f - fi / (un + 1e-8f);
        }
    } else if (w == 2) {
        // spatial: pair_sum = sum_{i,j} m_i m_j dist(i,j), dist computed on the fly
        bool  mj = p_lane > 0.5f;
        float px = s_pos[lane * 3 + 0];
        float py = s_pos[lane * 3 + 1];
        float pz = s_pos[lane * 3 + 2];
        float tj = 0.0f;
        for (int i = 0; i < 64; i++) {
            float dx = s_pos[i * 3 + 0] - px;
            float dy = s_pos[i * 3 + 1] - py;
            float dz = s_pos[i * 3 + 2] - pz;
            float d2 = dx * dx + dy * dy + dz * dz;
            bool on = (i != lane) && (s_p[i] > 0.5f);
            tj += on ? sqrtf(d2) : 0.0f;
        }
        float pair = wred(mj ? tj : 0.0f);
        unsigned long long bal = __ballot(mj);
        int nm = __popcll(bal);
        if (lane == 0) {
            s_part[4] = (nm >= 2) ? pair / fmaxf((float)nm * (float)(nm - 1), 1.0f) : 0.0f;
        }
    } else {
        // network coherence: p^T W p
        float tj = 0.0f;
        for (int i = 0; i < 64; i++) tj += s_p[i] * conn[i * 64 + lane];
        float coh = wred(tj * p_lane);
        if (lane == 0) s_part[5] = -coh * (1.0f / 4096.0f);
    }
    __syncthreads();

    if (tid == 0) {
        // per-row loss contribution (unscaled by 1/B; finalize kernel does that)
        partial[b] = 3.0f * s_part[1] * (1.0f / 64.0f)  // score (per-row mean over C)
                   + s_part[2]                           // margin
                   + 2.0f * s_part[3]                    // topk
                   + s_part[0] * (1.0f / 12.0f)          // contrastive
                   + 0.5f * s_part[4]                    // spatial
                   + 0.5f * s_part[5];                   // network
    }
}

__global__ void finalize_kernel(const float* __restrict__ partial, float* __restrict__ out) {
    __shared__ float sm[4];
    const int tid  = threadIdx.x;
    const int w    = tid >> 6;
    const int lane = tid & 63;
    float s = 0.0f;
    for (int i = tid; i < B_N; i += 256) s += partial[i];
    s = wred(s);
    if (lane == 0) sm[w] = s;
    __syncthreads();
    if (tid == 0) out[0] = (sm[0] + sm[1] + sm[2] + sm[3]) * (1.0f / (float)B_N);
}

extern "C" void kernel_launch(void* const* d_in, const int* in_sizes, int n_in,
                              void* d_out, int out_size, void* d_ws, size_t ws_size,
                              hipStream_t stream) {
    const float* pred = (const float*)d_in[0];
    const int*   lab  = (const int*)d_in[1];
    const float* emb  = (const float*)d_in[2];
    const float* cpos = (const float*)d_in[3];
    const float* conn = (const float*)d_in[4];
    float* out = (float*)d_out;
    float* partial = (float*)d_ws;  // 2048 floats = 8 KB, well within ws_size

    loss_kernel<<<B_N, 256, 0, stream>>>(pred, lab, emb, cpos, conn, partial);
    finalize_kernel<<<1, 256, 0, stream>>>(partial, out);
}